// Round 1
// baseline (68.520 us; speedup 1.0000x reference)
//
#include <hip/hip_runtime.h>
#include <math.h>

#define TPB 256
#define CH  32

static constexpr int B_    = 64;
static constexpr int S_    = 2048;
static constexpr int TOTAL = B_ * S_;        // 131072 samples
static constexpr int NBLK  = TOTAL / CH;     // 4096 blocks

// ---- constant tables (order irrelevant for means) ----
__constant__ int BS_[49] = {0,1,1,2,3,5,6,4,7,
    8,8,8,8,8,9,10,11,13,14,15,17,18,19,21,22,23,25,26,27,
    29,29,29,29,29,30,31,32,34,35,36,38,39,40,42,43,44,46,47,48};
__constant__ int BE_[49] = {1,2,5,3,4,6,7,8,29,
    9,13,17,21,25,10,11,12,14,15,16,18,19,20,22,23,24,26,27,28,
    30,34,38,42,46,31,32,33,35,36,37,39,40,41,43,44,45,47,48,49};
__constant__ float BMIN_[49] = {0.05f,0.1f,0.1f,0.2f,0.2f,0.2f,0.2f,0.05f,0.05f,
    0.01f,0.01f,0.01f,0.01f,0.01f,0.01f,0.01f,0.01f,0.01f,0.01f,
    0.01f,0.01f,0.01f,0.01f,0.01f,0.01f,0.01f,0.01f,0.01f,0.01f,
    0.01f,0.01f,0.01f,0.01f,0.01f,0.01f,0.01f,0.01f,0.01f,0.01f,
    0.01f,0.01f,0.01f,0.01f,0.01f,0.01f,0.01f,0.01f,0.01f,0.01f};
__constant__ float BMAX_[49] = {0.15f,0.2f,0.2f,0.35f,0.35f,0.35f,0.35f,0.15f,0.15f,
    0.08f,0.08f,0.08f,0.08f,0.08f,0.08f,0.08f,0.08f,0.08f,0.08f,
    0.08f,0.08f,0.08f,0.08f,0.08f,0.08f,0.08f,0.08f,0.08f,0.08f,
    0.08f,0.08f,0.08f,0.08f,0.08f,0.08f,0.08f,0.08f,0.08f,0.08f,
    0.08f,0.08f,0.08f,0.08f,0.08f,0.08f,0.08f,0.08f,0.08f,0.08f};
__constant__ int CS_[49] = {0,1,2,3,1,5,6,7,8,8,8,8,8,9,10,11,13,14,15,17,18,19,
    21,22,23,25,26,27,4,29,29,29,29,29,30,31,32,34,35,36,38,39,40,42,43,44,46,47,48};
__constant__ int CE_[49] = {1,2,3,4,5,6,7,8,9,13,17,21,25,10,11,12,14,15,16,18,19,20,
    22,23,24,26,27,28,29,30,34,38,42,46,31,32,33,35,36,37,39,40,41,43,44,45,47,48,49};
__constant__ int SL_[24] = {8,9,10,11,12,13,14,15,16,17,18,19,20,21,22,23,24,25,26,27,28,2,3,4};
__constant__ int SR_[24] = {29,30,31,32,33,34,35,36,37,38,39,40,41,42,43,44,45,46,47,48,49,5,6,7};

__global__ __launch_bounds__(TPB) void pose_main(
    const float* __restrict__ pred, const float* __restrict__ tgt,
    float* __restrict__ part)
{
    __shared__ __align__(16) float Jl[(CH + 2) * 150];
    __shared__ __align__(16) float Tl[CH * 150];
    __shared__ float red[4][6];

    const int blk = blockIdx.x;
    const int tid = threadIdx.x;
    const long n0 = (long)blk * CH;
    const int nload = min(CH + 2, TOTAL - (int)n0);   // samples of pred to stage (incl. halo)

    // coalesced float4 staging (chunk base = blk*19200 B -> 16B aligned)
    {
        const float4* __restrict__ ps = (const float4*)(pred + n0 * 150);
        float4* Jl4 = (float4*)Jl;
        const int nj4 = nload * 150 / 4;
        for (int i = tid; i < nj4; i += TPB) Jl4[i] = ps[i];
        const float4* __restrict__ ts = (const float4*)(tgt + n0 * 150);
        float4* Tl4 = (float4*)Tl;
        for (int i = tid; i < (CH * 150 / 4); i += TPB) Tl4[i] = ts[i];
    }
    __syncthreads();

    const int s_base = (int)(n0 & (S_ - 1));   // s index of first sample in chunk
    float a_bone = 0.f, a_ang = 0.f, a_sym = 0.f, a_vel = 0.f, a_acc = 0.f, a_sup = 0.f;

    // ---- bone penalties: 32*49 items ----
    for (int i = tid; i < CH * 49; i += TPB) {
        const int li = i / 49, k = i - li * 49;
        const float* Jp = Jl + li * 150;
        const int e3 = BE_[k] * 3, s3 = BS_[k] * 3;
        const float dx = Jp[e3] - Jp[s3], dy = Jp[e3 + 1] - Jp[s3 + 1], dz = Jp[e3 + 2] - Jp[s3 + 2];
        const float bl = sqrtf(dx * dx + dy * dy + dz * dz);
        a_bone += fmaxf(bl - BMAX_[k], 0.f) + fmaxf(BMIN_[k] - bl, 0.f);
    }

    // ---- supervised |pb - tb|: 32*49 items ----
    for (int i = tid; i < CH * 49; i += TPB) {
        const int li = i / 49, k = i - li * 49;
        const float* Jp = Jl + li * 150;
        const float* Tp = Tl + li * 150;
        const int e3 = CE_[k] * 3, s3 = CS_[k] * 3;
        const float dx = Jp[e3] - Jp[s3], dy = Jp[e3 + 1] - Jp[s3 + 1], dz = Jp[e3 + 2] - Jp[s3 + 2];
        const float pb = sqrtf(dx * dx + dy * dy + dz * dz);
        const float tx = Tp[e3] - Tp[s3], ty = Tp[e3 + 1] - Tp[s3 + 1], tz = Tp[e3 + 2] - Tp[s3 + 2];
        const float tb = sqrtf(tx * tx + ty * ty + tz * tz);
        a_sup += fabsf(pb - tb);
    }

    // ---- angle penalties: 32*4 items ----
    {
        const int Aa[4] = {1, 1, 2, 5}, Bb[4] = {2, 5, 3, 6}, Cc[4] = {3, 6, 4, 7};
        for (int i = tid; i < CH * 4; i += TPB) {
            const int li = i >> 2, k = i & 3;
            const float* Jp = Jl + li * 150;
            const int a3 = Aa[k] * 3, b3 = Bb[k] * 3, c3 = Cc[k] * 3;
            const float v1x = Jp[a3] - Jp[b3], v1y = Jp[a3 + 1] - Jp[b3 + 1], v1z = Jp[a3 + 2] - Jp[b3 + 2];
            const float v2x = Jp[c3] - Jp[b3], v2y = Jp[c3 + 1] - Jp[b3 + 1], v2z = Jp[c3 + 2] - Jp[b3 + 2];
            const float n1 = fmaxf(sqrtf(v1x * v1x + v1y * v1y + v1z * v1z), 1e-12f);
            const float n2 = fmaxf(sqrtf(v2x * v2x + v2y * v2y + v2z * v2z), 1e-12f);
            float cosv = (v1x * v2x + v1y * v2y + v1z * v2z) / (n1 * n2);
            cosv = fminf(fmaxf(cosv, -1.f), 1.f);
            const float deg = acosf(cosv) * 57.29577951308232f;
            a_ang += fmaxf(30.f - deg, 0.f) + fmaxf(deg - 150.f, 0.f);
        }
    }

    // ---- symmetry: 32*24 items ----
    for (int i = tid; i < CH * 24; i += TPB) {
        const int li = i / 24, k = i - li * 24;
        const float* Jp = Jl + li * 150;
        const int l3 = SL_[k] * 3, r3 = SR_[k] * 3;
        a_sym += fabsf(Jp[l3] + Jp[r3])
               + 0.5f * (fabsf(Jp[l3 + 1] - Jp[r3 + 1]) + fabsf(Jp[l3 + 2] - Jp[r3 + 2]));
    }

    // ---- temporal vel + acc: 32*50 items (halo samples staged in LDS) ----
    for (int i = tid; i < CH * 50; i += TPB) {
        const int li = i / 50, j = i - li * 50;
        const int s = s_base + li;
        const float* p0 = Jl + li * 150 + j * 3;
        if (s < S_ - 1) {
            const float* p1 = p0 + 150;
            const float vx = p1[0] - p0[0], vy = p1[1] - p0[1], vz = p1[2] - p0[2];
            a_vel += sqrtf(vx * vx + vy * vy + vz * vz);
            if (s < S_ - 2) {
                const float* p2 = p1 + 150;
                const float ax = p2[0] - 2.f * p1[0] + p0[0];
                const float ay = p2[1] - 2.f * p1[1] + p0[1];
                const float az = p2[2] - 2.f * p1[2] + p0[2];
                a_acc += sqrtf(ax * ax + ay * ay + az * az);
            }
        }
    }

    // ---- block reduction (wave shuffle then cross-wave LDS) ----
    float vals[6] = {a_bone, a_ang, a_sym, a_vel, a_acc, a_sup};
    #pragma unroll
    for (int k = 0; k < 6; ++k)
        #pragma unroll
        for (int off = 32; off > 0; off >>= 1)
            vals[k] += __shfl_down(vals[k], off, 64);

    const int wid = tid >> 6, lane = tid & 63;
    if (lane == 0) {
        #pragma unroll
        for (int k = 0; k < 6; ++k) red[wid][k] = vals[k];
    }
    __syncthreads();
    if (tid == 0) {
        float* dst = part + (long)blk * 6;
        #pragma unroll
        for (int k = 0; k < 6; ++k)
            dst[k] = red[0][k] + red[1][k] + red[2][k] + red[3][k];
    }
}

__global__ __launch_bounds__(256) void pose_reduce(
    const float* __restrict__ part, float* __restrict__ out)
{
    __shared__ float red[4][6];
    const int tid = threadIdx.x;
    float a[6] = {0.f, 0.f, 0.f, 0.f, 0.f, 0.f};
    for (int i = tid; i < NBLK; i += 256) {
        const float* p = part + (long)i * 6;
        #pragma unroll
        for (int k = 0; k < 6; ++k) a[k] += p[k];
    }
    #pragma unroll
    for (int k = 0; k < 6; ++k)
        #pragma unroll
        for (int off = 32; off > 0; off >>= 1)
            a[k] += __shfl_down(a[k], off, 64);

    const int wid = tid >> 6, lane = tid & 63;
    if (lane == 0) {
        #pragma unroll
        for (int k = 0; k < 6; ++k) red[wid][k] = a[k];
    }
    __syncthreads();
    if (tid == 0) {
        float t[6];
        #pragma unroll
        for (int k = 0; k < 6; ++k) t[k] = red[0][k] + red[1][k] + red[2][k] + red[3][k];
        const float bone = t[0] * (1.f / ((float)TOTAL * 49.f));
        const float ang  = t[1] * (1.f / ((float)TOTAL * 4.f));
        const float sym  = t[2] * (1.f / ((float)TOTAL * 24.f));
        const float temporal = t[4] * (1.f / ((float)B_ * (float)(S_ - 2) * 50.f))
                             + 0.5f * t[3] * (1.f / ((float)B_ * (float)(S_ - 1) * 50.f));
        const float sup  = t[5] * (1.f / ((float)TOTAL * 49.f));
        out[0] = bone;
        out[1] = ang;
        out[2] = sym;
        out[3] = temporal;
        out[4] = sup;
        out[5] = bone + 0.5f * ang + 0.3f * sym + 0.2f * temporal + sup;
    }
}

extern "C" void kernel_launch(void* const* d_in, const int* in_sizes, int n_in,
                              void* d_out, int out_size, void* d_ws, size_t ws_size,
                              hipStream_t stream)
{
    const float* pred = (const float*)d_in[0];
    const float* tgt  = (const float*)d_in[1];
    float* part = (float*)d_ws;   // 4096 * 6 f32 = 96 KB
    pose_main<<<NBLK, TPB, 0, stream>>>(pred, tgt, part);
    pose_reduce<<<1, 256, 0, stream>>>(part, (float*)d_out);
}

// Round 2
// 53.719 us; speedup vs baseline: 1.2755x; 1.2755x over previous
//
#include <hip/hip_runtime.h>
#include <math.h>

#define TPB 256
#define CH  16            // samples per chunk
#define CPB 4             // chunks per block

static constexpr int B_    = 64;
static constexpr int S_    = 2048;
static constexpr int TOTAL = B_ * S_;              // 131072 samples
static constexpr int NCHUNK = TOTAL / CH;          // 8192
static constexpr int NBLK   = NCHUNK / CPB;        // 2048 blocks

// ---- union bone table: 11 body + 40 hand = 51 edges ----
// covers bone-penalty set (49) and supervised-connection set (49); 47 shared.
// conn-only edges (7,8),(4,29) get sentinel ranges (penalty == 0);
// bone-only edges (4,8),(7,29) get wsup = 0.
__constant__ int US_[51] = {0,1,1,2,3,5,6,4,7,7,4,
    8,8,8,8,8,9,10,11,13,14,15,17,18,19,21,22,23,25,26,27,
    29,29,29,29,29,30,31,32,34,35,36,38,39,40,42,43,44,46,47,48};
__constant__ int UE_[51] = {1,2,5,3,4,6,7,8,29,8,29,
    9,13,17,21,25,10,11,12,14,15,16,18,19,20,22,23,24,26,27,28,
    30,34,38,42,46,31,32,33,35,36,37,39,40,41,43,44,45,47,48,49};
__constant__ float UMIN_[51] = {0.05f,0.1f,0.1f,0.2f,0.2f,0.2f,0.2f,0.05f,0.05f,-1e9f,-1e9f,
    0.01f,0.01f,0.01f,0.01f,0.01f,0.01f,0.01f,0.01f,0.01f,0.01f,
    0.01f,0.01f,0.01f,0.01f,0.01f,0.01f,0.01f,0.01f,0.01f,0.01f,
    0.01f,0.01f,0.01f,0.01f,0.01f,0.01f,0.01f,0.01f,0.01f,0.01f,
    0.01f,0.01f,0.01f,0.01f,0.01f,0.01f,0.01f,0.01f,0.01f,0.01f};
__constant__ float UMAX_[51] = {0.15f,0.2f,0.2f,0.35f,0.35f,0.35f,0.35f,0.15f,0.15f,1e9f,1e9f,
    0.08f,0.08f,0.08f,0.08f,0.08f,0.08f,0.08f,0.08f,0.08f,0.08f,
    0.08f,0.08f,0.08f,0.08f,0.08f,0.08f,0.08f,0.08f,0.08f,0.08f,
    0.08f,0.08f,0.08f,0.08f,0.08f,0.08f,0.08f,0.08f,0.08f,0.08f,
    0.08f,0.08f,0.08f,0.08f,0.08f,0.08f,0.08f,0.08f,0.08f,0.08f};
__constant__ float WSUP_[51] = {1.f,1.f,1.f,1.f,1.f,1.f,1.f,0.f,0.f,1.f,1.f,
    1.f,1.f,1.f,1.f,1.f,1.f,1.f,1.f,1.f,1.f,
    1.f,1.f,1.f,1.f,1.f,1.f,1.f,1.f,1.f,1.f,
    1.f,1.f,1.f,1.f,1.f,1.f,1.f,1.f,1.f,1.f,
    1.f,1.f,1.f,1.f,1.f,1.f,1.f,1.f,1.f,1.f};
__constant__ int SL_[24] = {8,9,10,11,12,13,14,15,16,17,18,19,20,21,22,23,24,25,26,27,28,2,3,4};
__constant__ int SR_[24] = {29,30,31,32,33,34,35,36,37,38,39,40,41,42,43,44,45,46,47,48,49,5,6,7};

__global__ __launch_bounds__(TPB) void pose_main(
    const float* __restrict__ pred, const float* __restrict__ tgt,
    float* __restrict__ part)
{
    __shared__ __align__(16) float Jl[(CH + 2) * 150];   // 10800 B
    __shared__ __align__(16) float Tl[CH * 150];         //  9600 B  (total 20400 -> 8 blk/CU)

    const int blk = blockIdx.x;
    const int tid = threadIdx.x;

    float a_bone = 0.f, a_ang = 0.f, a_sym = 0.f, a_vel = 0.f, a_acc = 0.f, a_sup = 0.f;

    for (int c = 0; c < CPB; ++c) {
        const int chunk = blk * CPB + c;
        const long n0 = (long)chunk * CH;
        const int nload = min(CH + 2, TOTAL - (int)n0);
        const int s_base = (int)(n0 & (S_ - 1));

        __syncthreads();   // LDS reuse guard
        {
            const float4* __restrict__ ps = (const float4*)(pred + n0 * 150);
            float4* Jl4 = (float4*)Jl;
            const int nj4 = nload * 150 / 4;
            for (int i = tid; i < nj4; i += TPB) Jl4[i] = ps[i];
            const float4* __restrict__ ts = (const float4*)(tgt + n0 * 150);
            float4* Tl4 = (float4*)Tl;
            for (int i = tid; i < CH * 150 / 4; i += TPB) Tl4[i] = ts[i];
        }
        __syncthreads();

        // ---- fused bone-penalty + supervised over 51-edge union: 16*51 items ----
        for (int i = tid; i < CH * 51; i += TPB) {
            const int li = i & 15, k = i >> 4;
            const float* Jp = Jl + li * 150;
            const float* Tp = Tl + li * 150;
            const int e3 = UE_[k] * 3, s3 = US_[k] * 3;
            const float dx = Jp[e3] - Jp[s3], dy = Jp[e3+1] - Jp[s3+1], dz = Jp[e3+2] - Jp[s3+2];
            const float pb = sqrtf(dx*dx + dy*dy + dz*dz);
            a_bone += fmaxf(pb - UMAX_[k], 0.f) + fmaxf(UMIN_[k] - pb, 0.f);
            const float tx = Tp[e3] - Tp[s3], ty = Tp[e3+1] - Tp[s3+1], tz = Tp[e3+2] - Tp[s3+2];
            const float tb = sqrtf(tx*tx + ty*ty + tz*tz);
            a_sup += WSUP_[k] * fabsf(pb - tb);
        }

        // ---- angles: 16*4 items ----
        {
            const int Aa[4] = {1,1,2,5}, Bb[4] = {2,5,3,6}, Cc[4] = {3,6,4,7};
            for (int i = tid; i < CH * 4; i += TPB) {
                const int li = i & 15, k = i >> 4;
                const float* Jp = Jl + li * 150;
                const int a3 = Aa[k]*3, b3 = Bb[k]*3, c3 = Cc[k]*3;
                const float v1x = Jp[a3]-Jp[b3], v1y = Jp[a3+1]-Jp[b3+1], v1z = Jp[a3+2]-Jp[b3+2];
                const float v2x = Jp[c3]-Jp[b3], v2y = Jp[c3+1]-Jp[b3+1], v2z = Jp[c3+2]-Jp[b3+2];
                const float n12 = (v1x*v1x+v1y*v1y+v1z*v1z) * (v2x*v2x+v2y*v2y+v2z*v2z);
                const float inv = __frsqrt_rn(fmaxf(n12, 1e-24f));
                float cosv = (v1x*v2x + v1y*v2y + v1z*v2z) * inv;
                cosv = fminf(fmaxf(cosv, -1.f), 1.f);
                const float deg = acosf(cosv) * 57.29577951308232f;
                a_ang += fmaxf(30.f - deg, 0.f) + fmaxf(deg - 150.f, 0.f);
            }
        }

        // ---- symmetry: 16*24 items ----
        for (int i = tid; i < CH * 24; i += TPB) {
            const int li = i & 15, k = i >> 4;
            const float* Jp = Jl + li * 150;
            const int l3 = SL_[k]*3, r3 = SR_[k]*3;
            a_sym += fabsf(Jp[l3] + Jp[r3])
                   + 0.5f * (fabsf(Jp[l3+1] - Jp[r3+1]) + fabsf(Jp[l3+2] - Jp[r3+2]));
        }

        // ---- temporal vel + acc: 16*50 items (halo in LDS) ----
        for (int i = tid; i < CH * 50; i += TPB) {
            const int li = i & 15, j = i >> 4;
            const int s = s_base + li;
            const float* p0 = Jl + li * 150 + j * 3;
            if (s < S_ - 1) {
                const float* p1 = p0 + 150;
                const float vx = p1[0]-p0[0], vy = p1[1]-p0[1], vz = p1[2]-p0[2];
                a_vel += sqrtf(vx*vx + vy*vy + vz*vz);
                if (s < S_ - 2) {
                    const float* p2 = p1 + 150;
                    const float ax = p2[0] - 2.f*p1[0] + p0[0];
                    const float ay = p2[1] - 2.f*p1[1] + p0[1];
                    const float az = p2[2] - 2.f*p1[2] + p0[2];
                    a_acc += sqrtf(ax*ax + ay*ay + az*az);
                }
            }
        }
    }

    // ---- block reduction (shuffle, then cross-wave via reused LDS) ----
    __syncthreads();
    float vals[6] = {a_bone, a_ang, a_sym, a_vel, a_acc, a_sup};
    #pragma unroll
    for (int k = 0; k < 6; ++k)
        #pragma unroll
        for (int off = 32; off > 0; off >>= 1)
            vals[k] += __shfl_down(vals[k], off, 64);

    float* red = Jl;                 // reuse staging LDS
    const int wid = tid >> 6, lane = tid & 63;
    if (lane == 0) {
        #pragma unroll
        for (int k = 0; k < 6; ++k) red[wid * 6 + k] = vals[k];
    }
    __syncthreads();
    if (tid == 0) {
        float* dst = part + (long)blk * 6;
        #pragma unroll
        for (int k = 0; k < 6; ++k)
            dst[k] = red[0*6+k] + red[1*6+k] + red[2*6+k] + red[3*6+k];
    }
}

__global__ __launch_bounds__(256) void pose_reduce(
    const float* __restrict__ part, float* __restrict__ out)
{
    __shared__ float red[4][6];
    const int tid = threadIdx.x;
    float a[6] = {0.f,0.f,0.f,0.f,0.f,0.f};
    for (int i = tid; i < NBLK; i += 256) {
        const float* p = part + (long)i * 6;
        #pragma unroll
        for (int k = 0; k < 6; ++k) a[k] += p[k];
    }
    #pragma unroll
    for (int k = 0; k < 6; ++k)
        #pragma unroll
        for (int off = 32; off > 0; off >>= 1)
            a[k] += __shfl_down(a[k], off, 64);

    const int wid = tid >> 6, lane = tid & 63;
    if (lane == 0) {
        #pragma unroll
        for (int k = 0; k < 6; ++k) red[wid][k] = a[k];
    }
    __syncthreads();
    if (tid == 0) {
        float t[6];
        #pragma unroll
        for (int k = 0; k < 6; ++k) t[k] = red[0][k] + red[1][k] + red[2][k] + red[3][k];
        const float bone = t[0] * (1.f / ((float)TOTAL * 49.f));
        const float ang  = t[1] * (1.f / ((float)TOTAL * 4.f));
        const float sym  = t[2] * (1.f / ((float)TOTAL * 24.f));
        const float temporal = t[4] * (1.f / ((float)B_ * (float)(S_ - 2) * 50.f))
                             + 0.5f * t[3] * (1.f / ((float)B_ * (float)(S_ - 1) * 50.f));
        const float sup  = t[5] * (1.f / ((float)TOTAL * 49.f));
        out[0] = bone;
        out[1] = ang;
        out[2] = sym;
        out[3] = temporal;
        out[4] = sup;
        out[5] = bone + 0.5f * ang + 0.3f * sym + 0.2f * temporal + sup;
    }
}

extern "C" void kernel_launch(void* const* d_in, const int* in_sizes, int n_in,
                              void* d_out, int out_size, void* d_ws, size_t ws_size,
                              hipStream_t stream)
{
    const float* pred = (const float*)d_in[0];
    const float* tgt  = (const float*)d_in[1];
    float* part = (float*)d_ws;   // 2048 * 6 f32 = 48 KB
    pose_main<<<NBLK, TPB, 0, stream>>>(pred, tgt, part);
    pose_reduce<<<1, 256, 0, stream>>>(part, (float*)d_out);
}